// Round 5
// baseline (479.136 us; speedup 1.0000x reference)
//
#include <hip/hip_runtime.h>
#include <math.h>

typedef unsigned long long u64;
typedef unsigned int u32;

#define BF 8
#define NPTS 16384
#define M_SN 1024
#define CCH 64
#define KNN 16
#define NTHR1 1024
#define KPER 16            // NPTS / NTHR1
#define TBL 4096
#define CCAP 3072
#define REM 1008           // M - 16 gripper slots

// output layout (flat float32, concatenated in return order)
constexpr size_t O0 = 0;                 // neighbor_feats 8*1024*16*64
constexpr size_t O1 = 8388608;           // supernode_xyz 8*1024*3
constexpr size_t O2 = 8413184;           // neighbor_mask 8*1024*16
constexpr size_t O3 = 8544256;           // out_idx 8*1024
constexpr size_t O4 = 8552448;           // out_valid 8*1024
constexpr size_t O5 = 8560640;           // out_bucket 8*1024

__device__ __forceinline__ bool is_valid_el(const void* vp, int mode, long long i) {
  if (mode == 1) return ((const unsigned char*)vp)[i] != 0;
  if (mode == 2) return ((const float*)vp)[i] != 0.0f;
  return ((const int*)vp)[i] != 0;
}

// monotone-decreasing encode: larger float -> smaller u32 (NaN sorts first; -inf last)
__device__ __forceinline__ u32 desc_enc(float f) {
  u32 u = __float_as_uint(f);
  u32 s = (u & 0x80000000u) ? ~u : (u | 0x80000000u);
  return ~s;
}
__device__ __forceinline__ bool enc_finite(u32 d) {
  u32 s = ~d;
  u32 u = (s & 0x80000000u) ? (s & 0x7FFFFFFFu) : ~s;
  return (u & 0x7F800000u) != 0x7F800000u;
}

__device__ __forceinline__ u64 wave_min_u64(u64 v) {
#pragma unroll
  for (int d = 32; d >= 1; d >>= 1) {
    u32 lo = __shfl_xor((u32)(v & 0xFFFFFFFFu), d, 64);
    u32 hi = __shfl_xor((u32)(v >> 32), d, 64);
    u64 o = ((u64)hi << 32) | lo;
    if (o < v) v = o;
  }
  return v;
}

__device__ __forceinline__ u64 shfl64_w64(u64 v, int src) {   // width-64 absolute lane
  u32 lo = (u32)__shfl((int)(u32)(v & 0xFFFFFFFFu), src, 64);
  u32 hi = (u32)__shfl((int)(u32)(v >> 32), src, 64);
  return ((u64)hi << 32) | lo;
}
__device__ __forceinline__ u64 shfl64_grp(u64 v, int src) {   // width-32 partitioned
  u32 lo = (u32)__shfl((int)(u32)(v & 0xFFFFFFFFu), src, 32);
  u32 hi = (u32)__shfl((int)(u32)(v >> 32), src, 32);
  return ((u64)hi << 32) | lo;
}
__device__ __forceinline__ u64 shflup64(u64 v, int width) {   // delta 1
  u32 lo = (u32)__shfl_up((int)(u32)(v & 0xFFFFFFFFu), 1, width);
  u32 hi = (u32)__shfl_up((int)(u32)(v >> 32), 1, width);
  return ((u64)hi << 32) | lo;
}

// block-wide min over 1024 threads; red16 is a dedicated u64[16] LDS array
__device__ __forceinline__ u64 block_min_u64(u64 v, u64* red16, int t) {
  v = wave_min_u64(v);
  if ((t & 63) == 0) red16[t >> 6] = v;
  __syncthreads();
  if (t < 64) {
    u64 x = red16[t & 15];
    x = wave_min_u64(x);
    if (t == 0) red16[0] = x;
  }
  __syncthreads();
  u64 r = red16[0];
  __syncthreads();
  return r;
}

// exclusive prefix-sum of val across 1024 threads
__device__ __forceinline__ int block_excl_scan(int val, int* scanb, int t, int* tot) {
  int incl = val;
#pragma unroll
  for (int d = 1; d < 64; d <<= 1) {
    int v = __shfl_up(incl, d, 64);
    if ((t & 63) >= d) incl += v;
  }
  if ((t & 63) == 63) scanb[t >> 6] = incl;
  __syncthreads();
  if (t < 64) {
    int ws = (t < 16) ? scanb[t] : 0;
#pragma unroll
    for (int d = 1; d < 16; d <<= 1) {
      int v = __shfl_up(ws, d, 64);
      if ((t & 63) >= d) ws += v;
    }
    if (t < 16) scanb[16 + t] = ws;
  }
  __syncthreads();
  int wv = t >> 6;
  int base = (wv == 0) ? 0 : scanb[16 + wv - 1];
  *tot = scanb[16 + 15];
  int r = base + incl - val;
  __syncthreads();
  return r;
}

// ---------------- K1: supernode sampling (one block per batch row) ----------------
__global__ __launch_bounds__(1024)
void sample_kernel(const float* __restrict__ xyz, const void* __restrict__ validp,
                   const float* __restrict__ state, const int* __restrict__ mask_id,
                   const float* __restrict__ extra, const float* __restrict__ glob,
                   int nwords, int* __restrict__ modep, float* __restrict__ out) {
  __shared__ u64 red16[16];
  __shared__ int table[TBL];        // 16 KB (mask min-index table, reused as histogram)
  __shared__ int scanb[32];
  __shared__ int mpick[REM];
  __shared__ u64 cand[CCAP];        // 24 KB
  __shared__ int gsorted[REM];
  __shared__ int head_i[16];
  __shared__ int head_bk[16];
  __shared__ int sh[8];             // 0:rhv 1:first_valid 2:has_radius 4:n_avail 5:cand_cnt 6:B 7:mode

  const int b = blockIdx.x, t = threadIdx.x;
  const float* xyzb = xyz + (size_t)b * NPTS * 3;
  const int* midb = mask_id + (size_t)b * NPTS;
  const float* exb = extra + (size_t)b * NPTS;
  const float* glb = glob + (size_t)b * NPTS;

  if (t < 8) sh[t] = 0;
  if (t == 1) sh[1] = 0x7FFFFFFF;
  if (t == 6) sh[6] = 0x7FFFFFFF;
  __syncthreads();

  // ---- inline storage-mode detection (first nwords words = safe lower bound) ----
  {
    const unsigned* wv = (const unsigned*)validp;
    int local = 0;
    for (int i = t; i < nwords; i += NTHR1) {
      unsigned w = wv[i];
      if (w == 0x3F800000u) local = 2;
      else if (w != 0u && w != 1u) local = max(local, 1);
    }
    if (local) atomicMax(&sh[7], local);
  }
  __syncthreads();
  const int vmode = sh[7];
  if (b == 0 && t == 0) modep[0] = vmode;   // all blocks agree; knn reads this

  // ---- validity bits (element i = k*1024 + t) ----
  u32 vbits = 0;
#pragma unroll
  for (int k = 0; k < KPER; k++) {
    int i = k * NTHR1 + t;
    if (is_valid_el(validp, vmode, (long long)b * NPTS + i)) vbits |= 1u << k;
  }
  if (vbits) {
    atomicOr(&sh[0], 1);
    atomicMin(&sh[1], (__ffs(vbits) - 1) * NTHR1 + t);
  }

  // ---- in-radius flag ----
  float gx = state[b * 8 + 0], gy = state[b * 8 + 1], gz = state[b * 8 + 2];
  u32 inr = 0;
#pragma unroll
  for (int k = 0; k < KPER; k++) {
    int i = k * NTHR1 + t;
    float dx = xyzb[3 * i] - gx, dy = xyzb[3 * i + 1] - gy, dz = xyzb[3 * i + 2] - gz;
    float d = sqrtf((dx * dx + dy * dy) + dz * dz);
    if (((vbits >> k) & 1u) && d <= 0.1f) inr |= 1u << k;
  }
  if (inr) atomicOr(&sh[2], 1);
  __syncthreads();

  const int rhv = sh[0];
  const int first_valid = rhv ? sh[1] : 0;
  const int hasrad = sh[2];
  u32 sel = 0;

  // ---- gripper stage: wave 0 runs a distributed sorted top-16 over all points ----
  if (t < 64) {
    u64 lst = ~0ull, kth = ~0ull;
    for (int p0 = 0; p0 < NPTS; p0 += 64) {
      int i = p0 + t;
      float dx = xyzb[3 * i] - gx, dy = xyzb[3 * i + 1] - gy, dz = xyzb[3 * i + 2] - gz;
      float d = sqrtf((dx * dx + dy * dy) + dz * dz);
      bool vv = is_valid_el(validp, vmode, (long long)b * NPTS + i);
      bool eligp = vv && (d <= 0.1f || !hasrad);
      u64 key = eligp ? (((u64)__float_as_uint(d) << 32) | (u32)i) : ~0ull;
      if (__any(key < kth)) {
        u64 bal = __ballot(key < kth);
        while (bal) {
          int bb = __ffsll(bal) - 1;
          bal &= bal - 1;
          u64 k = shfl64_w64(key, bb);
          if (k < kth) {
            bool gt = lst > k;
            u64 shv = shflup64(lst, 64);
            int pg = __shfl_up(gt ? 1 : 0, 1, 64);
            if (t == 0) pg = 0;
            lst = gt ? (pg ? shv : k) : lst;
            kth = shfl64_w64(lst, 15);
          }
        }
      }
    }
    if (t < 16) {
      bool keep = (lst >> 32) < 0x7F800000ull;
      head_i[t] = keep ? (int)(lst & 0xFFFFFFFFu) : first_valid;
      head_bk[t] = keep ? 1 : -1;
    }
  }
  __syncthreads();
#pragma unroll 1
  for (int j = 0; j < 16; j++) {
    if (head_bk[j] == 1) {
      int p = head_i[j];
      if ((p & (NTHR1 - 1)) == t) sel |= 1u << (p >> 10);
    }
  }

  // ---- mask stage: min index per distinct mask_id (read-guarded atomicMin) ----
  for (int j = t; j < TBL; j += NTHR1) table[j] = 0x7FFFFFFF;
  __syncthreads();
#pragma unroll
  for (int k = 0; k < KPER; k++) {
    if (((vbits >> k) & 1u) && !((sel >> k) & 1u)) {
      int i = k * NTHR1 + t;
      int id = midb[i];
      if ((u32)id < TBL && i < table[id]) atomicMin(&table[id], i);   // monotone: guard is exact
    }
  }
  __syncthreads();
  int cnt = 0;
#pragma unroll
  for (int q = 0; q < 4; q++) cnt += (table[4 * t + q] != 0x7FFFFFFF);
  int mtot;
  int excl = block_excl_scan(cnt, scanb, t, &mtot);
  {
    int pos = excl;
#pragma unroll
    for (int q = 0; q < 4; q++) {
      int v = table[4 * t + q];
      if (v != 0x7FFFFFFF) { if (pos < REM) mpick[pos] = v; pos++; }
    }
  }
  __syncthreads();
  const int nm = min(mtot, REM);
  for (int j = 0; j < nm; j++) {
    int p = mpick[j];
    if ((p & (NTHR1 - 1)) == t) sel |= 1u << (p >> 10);
  }

  // ---- extra stage (only active when < 8 distinct mask ids; not on bench data) ----
  u32 extra_used = 0;
  if (nm < 8 && rhv) {
    u32 extrbits = 0;
    for (int j = 0; j < 8; j++) {
      u64 best = ~0ull;
#pragma unroll
      for (int k = 0; k < KPER; k++) {
        if (((vbits >> k) & 1u) && !((sel >> k) & 1u) && !((extrbits >> k) & 1u)) {
          int i = k * NTHR1 + t;
          u64 key = ((u64)desc_enc(exb[i]) << 32) | (u32)i;
          if (key < best) best = key;
        }
      }
      u64 w = block_min_u64(best, red16, t);
      if (w == ~0ull) break;
      int idx = (int)(w & 0xFFFFFFFFu);
      bool fin = enc_finite((u32)(w >> 32));
      if ((idx & (NTHR1 - 1)) == t) extrbits |= 1u << (idx >> 10);
      if (j >= nm && fin) {
        extra_used |= 1u << j;
        if (t == 0) mpick[j] = idx;
        if ((idx & (NTHR1 - 1)) == t) sel |= 1u << (idx >> 10);
      }
    }
    __syncthreads();
  }

  // ---- global stage: exact ordered top-1008 of (global_score desc, idx asc) ----
  for (int j = t; j < TBL; j += NTHR1) table[j] = 0;
  for (int j = t; j < REM; j += NTHR1) gsorted[j] = -1;
  __syncthreads();
  u32 cbits = vbits & ~sel;
  atomicAdd(&sh[4], __popc(cbits));
  u32 dk[KPER];
#pragma unroll
  for (int k = 0; k < KPER; k++) {
    if ((cbits >> k) & 1u) {
      dk[k] = desc_enc(glb[k * NTHR1 + t]);
      atomicAdd(&table[dk[k] >> 20], 1);
    }
  }
  __syncthreads();
  const int nav = sh[4];
  const int T = min(REM, nav);
  if (T > 0) {
    int c4 = table[4 * t] + table[4 * t + 1] + table[4 * t + 2] + table[4 * t + 3];
    int htot;
    int cum = block_excl_scan(c4, scanb, t, &htot);
#pragma unroll
    for (int q = 0; q < 4; q++) {
      int prev = cum;
      cum += table[4 * t + q];
      if (prev < T && cum >= T) atomicMin(&sh[6], 4 * t + q);
    }
    __syncthreads();
    const int B = sh[6];
#pragma unroll
    for (int k = 0; k < KPER; k++) {
      bool c = ((cbits >> k) & 1u) && (int)(dk[k] >> 20) <= B;
      u64 bal = __ballot(c);
      int wbase = 0;
      if ((t & 63) == 0 && bal) wbase = atomicAdd(&sh[5], (int)__popcll(bal));
      wbase = __shfl(wbase, 0, 64);
      if (c) {
        int pos = wbase + (int)__popcll(bal & ((1ull << (t & 63)) - 1ull));
        if (pos < CCAP) cand[pos] = ((u64)dk[k] << 32) | (u32)(k * NTHR1 + t);
      }
    }
    __syncthreads();
    int nc = min(sh[5], CCAP);
    if (sh[5] <= CCAP) {
      for (int c = t; c < nc; c += NTHR1) {
        u64 key = cand[c];
        int r = 0;
        for (int j = 0; j < nc; j++) r += (cand[j] < key);
        if (r < REM) {
          int ix = (int)(key & 0xFFFFFFFFu);
          gsorted[r] = enc_finite((u32)(key >> 32)) ? ix : (ix | (int)0x80000000);
        }
      }
    } else {
      // pathological-ties fallback: iterative extraction
      u32 gext = 0;
      for (int j = 0; j < T; j++) {
        u64 best = ~0ull;
#pragma unroll
        for (int k = 0; k < KPER; k++) {
          if (((cbits >> k) & 1u) && !((gext >> k) & 1u)) {
            u64 key = ((u64)dk[k] << 32) | (u32)(k * NTHR1 + t);
            if (key < best) best = key;
          }
        }
        u64 w = block_min_u64(best, red16, t);
        if (w == ~0ull) break;
        int idx = (int)(w & 0xFFFFFFFFu);
        if ((idx & (NTHR1 - 1)) == t) gext |= 1u << (idx >> 10);
        if (t == 0) gsorted[j] = enc_finite((u32)(w >> 32)) ? idx : (idx | (int)0x80000000);
      }
    }
    __syncthreads();
  }

  // ---- emit out_idx / out_valid / out_bucket / supernode_xyz ----
  {
    int slot = t;
    int idx, bucket;
    if (slot < 16) {
      idx = head_i[slot];
      bucket = head_bk[slot];
    } else {
      int jj = slot - 16;
      bool mk = (jj < nm) || (jj < 8 && ((extra_used >> jj) & 1u));
      if (mk) { idx = mpick[jj]; bucket = 2; }
      else {
        int g = gsorted[jj];
        if (rhv && g >= 0) { idx = g; bucket = 0; }
        else { idx = first_valid; bucket = -1; }
      }
    }
    bool ov = rhv && is_valid_el(validp, vmode, (long long)b * NPTS + idx);
    int ob = ov ? bucket : -1;
    size_t o = (size_t)b * M_SN + slot;
    out[O3 + o] = (float)idx;
    out[O4 + o] = ov ? 1.0f : 0.0f;
    out[O5 + o] = (float)ob;
    out[O1 + 3 * o + 0] = xyzb[3 * idx + 0];
    out[O1 + 3 * o + 1] = xyzb[3 * idx + 1];
    out[O1 + 3 * o + 2] = xyzb[3 * idx + 2];
  }
}

// ---------------- K2: KNN-16 + feature gather ----------------
// 16 supernodes per block of 256 threads; each contiguous 32-lane group owns
// TWO supernodes (each staged point read once serves 2 distance computations).
// Hot loop: 1 ds_read_b128 + ~10 VALU; accept via __any guard; exact u64
// (d2_bits<<32|idx) order enforced in the rare guarded path via group-shared
// distributed sorted top-16 (lane l = l-th smallest).
#define NTHR2 256
#define CH 2048

__global__ __launch_bounds__(256)
void knn_kernel(const float* __restrict__ x, const float* __restrict__ xyz,
                const void* __restrict__ validp, const int* __restrict__ modep,
                float* __restrict__ out) {
  __shared__ __align__(16) float4 st[CH];           // 32 KB
  __shared__ u64 wn[16 * KNN];                      // winners per supernode

  const int b = blockIdx.x >> 6;
  const int grp = blockIdx.x & 63;
  const int t = threadIdx.x;
  const int sl = t >> 5;             // group 0..7
  const int sub = t & 31;
  const int lanebase = t & 32;
  const int m1 = grp * 16 + sl;
  const int m2 = m1 + 8;
  const int vmode = modep[0];
  const float* xyzb = xyz + (size_t)b * NPTS * 3;

  const int s1 = (int)out[O3 + (size_t)b * M_SN + m1];
  const int s2 = (int)out[O3 + (size_t)b * M_SN + m2];
  const float ax1 = xyzb[3 * s1], ay1 = xyzb[3 * s1 + 1], az1 = xyzb[3 * s1 + 2];
  const float ax2 = xyzb[3 * s2], ay2 = xyzb[3 * s2 + 1], az2 = xyzb[3 * s2 + 2];
  const float sa1 = __fadd_rn(__fadd_rn(__fmul_rn(ax1, ax1), __fmul_rn(ay1, ay1)), __fmul_rn(az1, az1));
  const float sa2 = __fadd_rn(__fadd_rn(__fmul_rn(ax2, ax2), __fmul_rn(ay2, ay2)), __fmul_rn(az2, az2));

  u64 lst1 = ~0ull, kth1 = ~0ull, lst2 = ~0ull, kth2 = ~0ull;
  float thr1 = __uint_as_float(0xFFFFFFFFu);   // NaN: !(d2 > NaN) accepts all while unfilled
  float thr2 = thr1;

  for (int c0 = 0; c0 < NPTS; c0 += CH) {
    for (int p = t; p < CH; p += NTHR2) {
      float px = xyzb[3 * (c0 + p)], py = xyzb[3 * (c0 + p) + 1], pz = xyzb[3 * (c0 + p) + 2];
      bool v = is_valid_el(validp, vmode, (long long)b * NPTS + c0 + p);
      float sb = __fadd_rn(__fadd_rn(__fmul_rn(px, px), __fmul_rn(py, py)), __fmul_rn(pz, pz));
      st[p] = make_float4(px, py, pz, v ? sb : INFINITY);
    }
    __syncthreads();
#pragma unroll 4
    for (int j = 0; j < CH / 32; j++) {
      int p = sub + 32 * j;
      float4 v = st[p];
      // fmaf(-2,dot,s) == s - 2*dot bit-exact (x2 is exact); dot fma-contracted
      float dot1 = fmaf(ax1, v.x, fmaf(ay1, v.y, __fmul_rn(az1, v.z)));
      float dot2 = fmaf(ax2, v.x, fmaf(ay2, v.y, __fmul_rn(az2, v.z)));
      float d21 = fmaf(-2.0f, dot1, __fadd_rn(sa1, v.w));
      float d22 = fmaf(-2.0f, dot2, __fadd_rn(sa2, v.w));
      bool c1 = !(d21 > thr1);
      bool c2 = !(d22 > thr2);
      if (__any(c1 | c2)) {
        int gi = c0 + p;
        u64 key1 = ((u64)__float_as_uint(fmaxf(d21, 0.0f)) << 32) | (u32)gi;
        u64 key2 = ((u64)__float_as_uint(fmaxf(d22, 0.0f)) << 32) | (u32)gi;
        u32 mq1 = (u32)(__ballot(c1) >> lanebase);
        u32 mq2 = (u32)(__ballot(c2) >> lanebase);
        while (mq1) {
          int bb = __ffs(mq1) - 1;
          mq1 &= mq1 - 1;
          u64 k = shfl64_w64(key1, lanebase + bb);
          if (k < kth1) {
            bool gt = lst1 > k;
            u64 shv = shflup64(lst1, 32);
            int pg = __shfl_up(gt ? 1 : 0, 1, 32);
            if (sub == 0) pg = 0;
            lst1 = gt ? (pg ? shv : k) : lst1;
            kth1 = shfl64_grp(lst1, 15);
            thr1 = __uint_as_float((u32)(kth1 >> 32));
          }
        }
        while (mq2) {
          int bb = __ffs(mq2) - 1;
          mq2 &= mq2 - 1;
          u64 k = shfl64_w64(key2, lanebase + bb);
          if (k < kth2) {
            bool gt = lst2 > k;
            u64 shv = shflup64(lst2, 32);
            int pg = __shfl_up(gt ? 1 : 0, 1, 32);
            if (sub == 0) pg = 0;
            lst2 = gt ? (pg ? shv : k) : lst2;
            kth2 = shfl64_grp(lst2, 15);
            thr2 = __uint_as_float((u32)(kth2 >> 32));
          }
        }
      }
    }
    __syncthreads();
  }

  if (sub < KNN) {
    wn[sl * KNN + sub] = lst1;          // lane l = l-th nearest, exact order
    wn[(sl + 8) * KNN + sub] = lst2;
  }
  __syncthreads();

  // emit neighbor_mask + gather features (1 thread per (supernode,k) row)
  {
    int sn = t >> 4;            // 0..15
    int k2 = t & 15;
    int mm = grp * 16 + sn;
    u64 key = wn[sn * KNN + k2];
    bool fin = (u32)(key >> 32) < 0x7F800000u;
    int ni = fin ? (int)(key & 0xFFFFFFFFu) : 0;
    size_t o2 = ((size_t)b * M_SN + mm) * KNN + k2;
    out[O2 + o2] = fin ? 1.0f : 0.0f;
    const float4* src = (const float4*)(x + ((size_t)b * NPTS + ni) * CCH);
    float4* dst = (float4*)(out + O0 + o2 * CCH);
#pragma unroll
    for (int q = 0; q < 16; q++) dst[q] = src[q];
  }
}

extern "C" void kernel_launch(void* const* d_in, const int* in_sizes, int n_in,
                              void* d_out, int out_size, void* d_ws, size_t ws_size,
                              hipStream_t stream) {
  const float* x = (const float*)d_in[0];
  const float* xyz = (const float*)d_in[1];
  const void* valid = d_in[2];
  const float* state = (const float*)d_in[3];
  const int* mask_id = (const int*)d_in[4];
  const float* extra = (const float*)d_in[5];
  const float* glob = (const float*)d_in[6];
  float* out = (float*)d_out;
  int* modep = (int*)d_ws;

  sample_kernel<<<BF, NTHR1, 0, stream>>>(xyz, valid, state, mask_id, extra, glob,
                                          in_sizes[2] / 4, modep, out);
  knn_kernel<<<BF * 64, NTHR2, 0, stream>>>(x, xyz, valid, modep, out);
}

// Round 6
// 374.571 us; speedup vs baseline: 1.2792x; 1.2792x over previous
//
#include <hip/hip_runtime.h>
#include <math.h>

typedef unsigned long long u64;
typedef unsigned int u32;

#define BF 8
#define NPTS 16384
#define M_SN 1024
#define CCH 64
#define KNN 16
#define NTHR1 1024
#define KPER 16            // NPTS / NTHR1
#define TBL 4096
#define CCAP 3072
#define REM 1008           // M - 16 gripper slots

// output layout (flat float32, concatenated in return order)
constexpr size_t O0 = 0;                 // neighbor_feats 8*1024*16*64
constexpr size_t O1 = 8388608;           // supernode_xyz 8*1024*3
constexpr size_t O2 = 8413184;           // neighbor_mask 8*1024*16
constexpr size_t O3 = 8544256;           // out_idx 8*1024
constexpr size_t O4 = 8552448;           // out_valid 8*1024
constexpr size_t O5 = 8560640;           // out_bucket 8*1024

__device__ __forceinline__ bool is_valid_el(const void* vp, int mode, long long i) {
  if (mode == 1) return ((const unsigned char*)vp)[i] != 0;
  if (mode == 2) return ((const float*)vp)[i] != 0.0f;
  return ((const int*)vp)[i] != 0;
}

// monotone-decreasing encode: larger float -> smaller u32 (NaN sorts first; -inf last)
__device__ __forceinline__ u32 desc_enc(float f) {
  u32 u = __float_as_uint(f);
  u32 s = (u & 0x80000000u) ? ~u : (u | 0x80000000u);
  return ~s;
}
__device__ __forceinline__ bool enc_finite(u32 d) {
  u32 s = ~d;
  u32 u = (s & 0x80000000u) ? (s & 0x7FFFFFFFu) : ~s;
  return (u & 0x7F800000u) != 0x7F800000u;
}

__device__ __forceinline__ u64 wave_min_u64(u64 v) {
#pragma unroll
  for (int d = 32; d >= 1; d >>= 1) {
    u32 lo = __shfl_xor((u32)(v & 0xFFFFFFFFu), d, 64);
    u32 hi = __shfl_xor((u32)(v >> 32), d, 64);
    u64 o = ((u64)hi << 32) | lo;
    if (o < v) v = o;
  }
  return v;
}

__device__ __forceinline__ u64 shfl64_w64(u64 v, int src) {   // width-64 absolute lane
  u32 lo = (u32)__shfl((int)(u32)(v & 0xFFFFFFFFu), src, 64);
  u32 hi = (u32)__shfl((int)(u32)(v >> 32), src, 64);
  return ((u64)hi << 32) | lo;
}
__device__ __forceinline__ u64 shfl64_grp(u64 v, int src) {   // width-32 partitioned
  u32 lo = (u32)__shfl((int)(u32)(v & 0xFFFFFFFFu), src, 32);
  u32 hi = (u32)__shfl((int)(u32)(v >> 32), src, 32);
  return ((u64)hi << 32) | lo;
}
__device__ __forceinline__ u64 shflup64(u64 v, int width) {   // delta 1
  u32 lo = (u32)__shfl_up((int)(u32)(v & 0xFFFFFFFFu), 1, width);
  u32 hi = (u32)__shfl_up((int)(u32)(v >> 32), 1, width);
  return ((u64)hi << 32) | lo;
}

// block-wide min over 1024 threads; red16 is a dedicated u64[16] LDS array
__device__ __forceinline__ u64 block_min_u64(u64 v, u64* red16, int t) {
  v = wave_min_u64(v);
  if ((t & 63) == 0) red16[t >> 6] = v;
  __syncthreads();
  if (t < 64) {
    u64 x = red16[t & 15];
    x = wave_min_u64(x);
    if (t == 0) red16[0] = x;
  }
  __syncthreads();
  u64 r = red16[0];
  __syncthreads();
  return r;
}

// exclusive prefix-sum of val across 1024 threads
__device__ __forceinline__ int block_excl_scan(int val, int* scanb, int t, int* tot) {
  int incl = val;
#pragma unroll
  for (int d = 1; d < 64; d <<= 1) {
    int v = __shfl_up(incl, d, 64);
    if ((t & 63) >= d) incl += v;
  }
  if ((t & 63) == 63) scanb[t >> 6] = incl;
  __syncthreads();
  if (t < 64) {
    int ws = (t < 16) ? scanb[t] : 0;
#pragma unroll
    for (int d = 1; d < 16; d <<= 1) {
      int v = __shfl_up(ws, d, 64);
      if ((t & 63) >= d) ws += v;
    }
    if (t < 16) scanb[16 + t] = ws;
  }
  __syncthreads();
  int wv = t >> 6;
  int base = (wv == 0) ? 0 : scanb[16 + wv - 1];
  *tot = scanb[16 + 15];
  int r = base + incl - val;
  __syncthreads();
  return r;
}

// ---------------- K1: supernode sampling (one block per batch row) ----------------
__global__ __launch_bounds__(1024, 1)
void sample_kernel(const float* __restrict__ xyz, const void* __restrict__ validp,
                   const float* __restrict__ state, const int* __restrict__ mask_id,
                   const float* __restrict__ extra, const float* __restrict__ glob,
                   int nwords, int* __restrict__ modep, float* __restrict__ out) {
  __shared__ u64 red16[16];
  __shared__ u64 gmerge[256];       // per-wave gripper top-16 lists
  __shared__ int table[TBL];        // 16 KB (mask min-index table, reused as histogram)
  __shared__ int scanb[32];
  __shared__ int mpick[REM];
  __shared__ u64 cand[CCAP];        // 24 KB
  __shared__ int gsorted[REM];
  __shared__ int head_i[16];
  __shared__ int head_bk[16];
  __shared__ int sh[8];             // 0:rhv 1:first_valid 2:has_radius 4:n_avail 5:cand_cnt 6:B 7:mode

  const int b = blockIdx.x, t = threadIdx.x;
  const float* xyzb = xyz + (size_t)b * NPTS * 3;
  const int* midb = mask_id + (size_t)b * NPTS;
  const float* exb = extra + (size_t)b * NPTS;
  const float* glb = glob + (size_t)b * NPTS;

  if (t < 8) sh[t] = 0;
  if (t == 1) sh[1] = 0x7FFFFFFF;
  if (t == 6) sh[6] = 0x7FFFFFFF;
  __syncthreads();

  // ---- inline storage-mode detection ----
  {
    const unsigned* wv = (const unsigned*)validp;
    int local = 0;
    for (int i = t; i < nwords; i += NTHR1) {
      unsigned w = wv[i];
      if (w == 0x3F800000u) local = 2;
      else if (w != 0u && w != 1u) local = max(local, 1);
    }
    if (local) atomicMax(&sh[7], local);
  }
  __syncthreads();
  const int vmode = sh[7];
  if (b == 0 && t == 0) modep[0] = vmode;   // all blocks agree; knn reads this

  // ---- validity bits + hoisted mask ids (element i = k*1024 + t) ----
  u32 vbits = 0;
  int mid[KPER];
#pragma unroll
  for (int k = 0; k < KPER; k++) {
    int i = k * NTHR1 + t;
    if (is_valid_el(validp, vmode, (long long)b * NPTS + i)) vbits |= 1u << k;
    mid[k] = midb[i];
  }
  if (vbits) {
    atomicOr(&sh[0], 1);
    atomicMin(&sh[1], (__ffs(vbits) - 1) * NTHR1 + t);
  }

  // ---- gripper distances (kept in registers) + in-radius flag ----
  float gx = state[b * 8 + 0], gy = state[b * 8 + 1], gz = state[b * 8 + 2];
  float gd[KPER];
  u32 inr = 0;
#pragma unroll
  for (int k = 0; k < KPER; k++) {
    int i = k * NTHR1 + t;
    float dx = xyzb[3 * i] - gx, dy = xyzb[3 * i + 1] - gy, dz = xyzb[3 * i + 2] - gz;
    float d = sqrtf((dx * dx + dy * dy) + dz * dz);
    gd[k] = d;
    if (((vbits >> k) & 1u) && d <= 0.1f) inr |= 1u << k;
  }
  if (inr) atomicOr(&sh[2], 1);
  __syncthreads();

  const int rhv = sh[0];
  const int first_valid = rhv ? sh[1] : 0;
  const int hasrad = sh[2];
  u32 sel = 0;

  // ---- gripper stage: per-wave distributed top-16 from registers, then 1-wave merge ----
  {
    const u32 elig = vbits & (hasrad ? inr : 0xFFFFu);
    const int ln = t & 63;
    u64 lst = ~0ull, kth = ~0ull;
#pragma unroll 1
    for (int k = 0; k < KPER; k++) {
      int i = k * NTHR1 + t;
      u64 key = ((elig >> k) & 1u) ? (((u64)__float_as_uint(gd[k]) << 32) | (u32)i) : ~0ull;
      u64 bal = __ballot(key < kth);
      while (bal) {
        int bb = __ffsll(bal) - 1;
        bal &= bal - 1;
        u64 kk = shfl64_w64(key, bb);
        if (kk < kth) {
          bool gt = lst > kk;
          u64 shv = shflup64(lst, 64);
          int pg = __shfl_up(gt ? 1 : 0, 1, 64);
          if (ln == 0) pg = 0;
          lst = gt ? (pg ? shv : kk) : lst;
          kth = shfl64_w64(lst, 15);
        }
      }
    }
    if (ln < 16) gmerge[(t >> 6) * 16 + ln] = lst;
  }
  __syncthreads();
  if (t < 64) {
    u64 lst = ~0ull, kth = ~0ull;
#pragma unroll 1
    for (int r = 0; r < 4; r++) {
      u64 key = gmerge[r * 64 + t];
      u64 bal = __ballot(key < kth);
      while (bal) {
        int bb = __ffsll(bal) - 1;
        bal &= bal - 1;
        u64 kk = shfl64_w64(key, bb);
        if (kk < kth) {
          bool gt = lst > kk;
          u64 shv = shflup64(lst, 64);
          int pg = __shfl_up(gt ? 1 : 0, 1, 64);
          if (t == 0) pg = 0;
          lst = gt ? (pg ? shv : kk) : lst;
          kth = shfl64_w64(lst, 15);
        }
      }
    }
    if (t < 16) {
      bool keep = (lst >> 32) < 0x7F800000ull;
      head_i[t] = keep ? (int)(lst & 0xFFFFFFFFu) : first_valid;
      head_bk[t] = keep ? 1 : -1;
    }
  }
  __syncthreads();
#pragma unroll 1
  for (int j = 0; j < 16; j++) {
    if (head_bk[j] == 1) {
      int p = head_i[j];
      if ((p & (NTHR1 - 1)) == t) sel |= 1u << (p >> 10);
    }
  }

  // ---- mask stage: min index per distinct mask_id (read-guarded atomicMin) ----
  for (int j = t; j < TBL; j += NTHR1) table[j] = 0x7FFFFFFF;
  __syncthreads();
#pragma unroll
  for (int k = 0; k < KPER; k++) {
    if (((vbits >> k) & 1u) && !((sel >> k) & 1u)) {
      int i = k * NTHR1 + t;
      int id = mid[k];
      if ((u32)id < TBL && i < table[id]) atomicMin(&table[id], i);   // monotone: guard is exact
    }
  }
  __syncthreads();
  int cnt = 0;
#pragma unroll
  for (int q = 0; q < 4; q++) cnt += (table[4 * t + q] != 0x7FFFFFFF);
  int mtot;
  int excl = block_excl_scan(cnt, scanb, t, &mtot);
  {
    int pos = excl;
#pragma unroll
    for (int q = 0; q < 4; q++) {
      int v = table[4 * t + q];
      if (v != 0x7FFFFFFF) { if (pos < REM) mpick[pos] = v; pos++; }
    }
  }
  __syncthreads();
  const int nm = min(mtot, REM);
  for (int j = 0; j < nm; j++) {
    int p = mpick[j];
    if ((p & (NTHR1 - 1)) == t) sel |= 1u << (p >> 10);
  }

  // ---- extra stage (only active when < 8 distinct mask ids; not on bench data) ----
  u32 extra_used = 0;
  if (nm < 8 && rhv) {
    u32 extrbits = 0;
    for (int j = 0; j < 8; j++) {
      u64 best = ~0ull;
#pragma unroll
      for (int k = 0; k < KPER; k++) {
        if (((vbits >> k) & 1u) && !((sel >> k) & 1u) && !((extrbits >> k) & 1u)) {
          int i = k * NTHR1 + t;
          u64 key = ((u64)desc_enc(exb[i]) << 32) | (u32)i;
          if (key < best) best = key;
        }
      }
      u64 w = block_min_u64(best, red16, t);
      if (w == ~0ull) break;
      int idx = (int)(w & 0xFFFFFFFFu);
      bool fin = enc_finite((u32)(w >> 32));
      if ((idx & (NTHR1 - 1)) == t) extrbits |= 1u << (idx >> 10);
      if (j >= nm && fin) {
        extra_used |= 1u << j;
        if (t == 0) mpick[j] = idx;
        if ((idx & (NTHR1 - 1)) == t) sel |= 1u << (idx >> 10);
      }
    }
    __syncthreads();
  }

  // ---- global stage: exact ordered top-1008 of (global_score desc, idx asc) ----
  for (int j = t; j < TBL; j += NTHR1) table[j] = 0;
  for (int j = t; j < REM; j += NTHR1) gsorted[j] = -1;
  __syncthreads();
  u32 cbits = vbits & ~sel;
  atomicAdd(&sh[4], __popc(cbits));
  u32 dk[KPER];
#pragma unroll
  for (int k = 0; k < KPER; k++) {
    if ((cbits >> k) & 1u) {
      dk[k] = desc_enc(glb[k * NTHR1 + t]);
      atomicAdd(&table[dk[k] >> 20], 1);
    }
  }
  __syncthreads();
  const int nav = sh[4];
  const int T = min(REM, nav);
  if (T > 0) {
    int c4 = table[4 * t] + table[4 * t + 1] + table[4 * t + 2] + table[4 * t + 3];
    int htot;
    int cum = block_excl_scan(c4, scanb, t, &htot);
#pragma unroll
    for (int q = 0; q < 4; q++) {
      int prev = cum;
      cum += table[4 * t + q];
      if (prev < T && cum >= T) atomicMin(&sh[6], 4 * t + q);
    }
    __syncthreads();
    const int B = sh[6];
#pragma unroll
    for (int k = 0; k < KPER; k++) {
      bool c = ((cbits >> k) & 1u) && (int)(dk[k] >> 20) <= B;
      u64 bal = __ballot(c);
      int wbase = 0;
      if ((t & 63) == 0 && bal) wbase = atomicAdd(&sh[5], (int)__popcll(bal));
      wbase = __shfl(wbase, 0, 64);
      if (c) {
        int pos = wbase + (int)__popcll(bal & ((1ull << (t & 63)) - 1ull));
        if (pos < CCAP) cand[pos] = ((u64)dk[k] << 32) | (u32)(k * NTHR1 + t);
      }
    }
    __syncthreads();
    int nc = min(sh[5], CCAP);
    if (sh[5] <= CCAP) {
      for (int c = t; c < nc; c += NTHR1) {
        u64 key = cand[c];
        int r = 0;
        for (int j = 0; j < nc; j++) r += (cand[j] < key);
        if (r < REM) {
          int ix = (int)(key & 0xFFFFFFFFu);
          gsorted[r] = enc_finite((u32)(key >> 32)) ? ix : (ix | (int)0x80000000);
        }
      }
    } else {
      // pathological-ties fallback: iterative extraction
      u32 gext = 0;
      for (int j = 0; j < T; j++) {
        u64 best = ~0ull;
#pragma unroll
        for (int k = 0; k < KPER; k++) {
          if (((cbits >> k) & 1u) && !((gext >> k) & 1u)) {
            u64 key = ((u64)dk[k] << 32) | (u32)(k * NTHR1 + t);
            if (key < best) best = key;
          }
        }
        u64 w = block_min_u64(best, red16, t);
        if (w == ~0ull) break;
        int idx = (int)(w & 0xFFFFFFFFu);
        if ((idx & (NTHR1 - 1)) == t) gext |= 1u << (idx >> 10);
        if (t == 0) gsorted[j] = enc_finite((u32)(w >> 32)) ? idx : (idx | (int)0x80000000);
      }
    }
    __syncthreads();
  }

  // ---- emit out_idx / out_valid / out_bucket / supernode_xyz ----
  {
    int slot = t;
    int idx, bucket;
    if (slot < 16) {
      idx = head_i[slot];
      bucket = head_bk[slot];
    } else {
      int jj = slot - 16;
      bool mk = (jj < nm) || (jj < 8 && ((extra_used >> jj) & 1u));
      if (mk) { idx = mpick[jj]; bucket = 2; }
      else {
        int g = gsorted[jj];
        if (rhv && g >= 0) { idx = g; bucket = 0; }
        else { idx = first_valid; bucket = -1; }
      }
    }
    bool ov = rhv && is_valid_el(validp, vmode, (long long)b * NPTS + idx);
    int ob = ov ? bucket : -1;
    size_t o = (size_t)b * M_SN + slot;
    out[O3 + o] = (float)idx;
    out[O4 + o] = ov ? 1.0f : 0.0f;
    out[O5 + o] = (float)ob;
    out[O1 + 3 * o + 0] = xyzb[3 * idx + 0];
    out[O1 + 3 * o + 1] = xyzb[3 * idx + 1];
    out[O1 + 3 * o + 2] = xyzb[3 * idx + 2];
  }
}

// ---------------- K2: KNN-16 + feature gather ----------------
// R4-measured structure: 8 supernodes per block of 256 threads, 1024 blocks
// (~12-16 waves/CU of latency hiding). Each contiguous 32-lane group owns one
// supernode; group-shared distributed sorted top-16 (lane l = l-th smallest
// u64 (d2_bits<<32|idx)); hot loop accept test = one scalar fp32 compare.
#define NTHR2 256
#define CH 2048
#define SPB 8      // supernodes per block

__global__ __launch_bounds__(256)
void knn_kernel(const float* __restrict__ x, const float* __restrict__ xyz,
                const void* __restrict__ validp, const int* __restrict__ modep,
                float* __restrict__ out) {
  __shared__ __align__(16) float4 st[CH];           // 32 KB
  __shared__ u64 wn[SPB * KNN];                     // winners per supernode

  const int b = blockIdx.x >> 7;
  const int grp = blockIdx.x & 127;
  const int t = threadIdx.x;
  const int sl = t >> 5;             // supernode within block (contiguous 32 lanes)
  const int sub = t & 31;
  const int lanebase = t & 32;
  const int m = grp * SPB + sl;
  const int vmode = modep[0];
  const float* xyzb = xyz + (size_t)b * NPTS * 3;

  const int sidx = (int)out[O3 + (size_t)b * M_SN + m];
  const float ax = xyzb[3 * sidx], ay = xyzb[3 * sidx + 1], az = xyzb[3 * sidx + 2];
  const float sa = __fadd_rn(__fadd_rn(__fmul_rn(ax, ax), __fmul_rn(ay, ay)), __fmul_rn(az, az));

  u64 lst = ~0ull, kth = ~0ull;
  float thr = __uint_as_float(0xFFFFFFFFu);   // NaN: !(d2 > NaN) accepts all while unfilled

  for (int c0 = 0; c0 < NPTS; c0 += CH) {
    for (int p = t; p < CH; p += NTHR2) {
      float px = xyzb[3 * (c0 + p)], py = xyzb[3 * (c0 + p) + 1], pz = xyzb[3 * (c0 + p) + 2];
      bool v = is_valid_el(validp, vmode, (long long)b * NPTS + c0 + p);
      float sb = __fadd_rn(__fadd_rn(__fmul_rn(px, px), __fmul_rn(py, py)), __fmul_rn(pz, pz));
      st[p] = make_float4(px, py, pz, v ? sb : INFINITY);
    }
    __syncthreads();
#pragma unroll 4
    for (int j = 0; j < CH / 32; j++) {
      int p = sub + 32 * j;
      float4 v = st[p];
      // fmaf(-2,dot,s) == s - 2*dot bit-exact (x2 exact); dot fma-contracted
      float dot = fmaf(ax, v.x, fmaf(ay, v.y, __fmul_rn(az, v.z)));
      float d2 = fmaf(-2.0f, dot, __fadd_rn(sa, v.w));
      bool c = !(d2 > thr);
      if (__any(c)) {
        u64 key = ((u64)__float_as_uint(fmaxf(d2, 0.0f)) << 32) | (u32)(c0 + p);
        u32 mq = (u32)(__ballot(c) >> lanebase);
        while (mq) {
          int bb = __ffs(mq) - 1;
          mq &= mq - 1;
          u64 k = shfl64_w64(key, lanebase + bb);
          if (k < kth) {
            bool gt = lst > k;
            u64 shv = shflup64(lst, 32);
            int pg = __shfl_up(gt ? 1 : 0, 1, 32);
            if (sub == 0) pg = 0;
            lst = gt ? (pg ? shv : k) : lst;
            kth = shfl64_grp(lst, 15);
            thr = __uint_as_float((u32)(kth >> 32));
          }
        }
      }
    }
    __syncthreads();
  }

  if (sub < KNN) wn[sl * KNN + sub] = lst;    // lane l = l-th nearest, exact order
  __syncthreads();

  // emit neighbor_mask + gather features (2 threads per (supernode,k) row)
  {
    int s2 = t >> 5;            // 0..7
    int k2 = (t >> 1) & 15;     // 0..15
    int half = t & 1;
    int mm = grp * SPB + s2;
    u64 key = wn[s2 * KNN + k2];
    bool fin = (u32)(key >> 32) < 0x7F800000u;
    int ni = fin ? (int)(key & 0xFFFFFFFFu) : 0;
    size_t o2 = ((size_t)b * M_SN + mm) * KNN + k2;
    if (half == 0) out[O2 + o2] = fin ? 1.0f : 0.0f;
    const float4* src = (const float4*)(x + ((size_t)b * NPTS + ni) * CCH);
    float4* dst = (float4*)(out + O0 + o2 * CCH);
#pragma unroll
    for (int q = 0; q < 8; q++) dst[half * 8 + q] = src[half * 8 + q];
  }
}

extern "C" void kernel_launch(void* const* d_in, const int* in_sizes, int n_in,
                              void* d_out, int out_size, void* d_ws, size_t ws_size,
                              hipStream_t stream) {
  const float* x = (const float*)d_in[0];
  const float* xyz = (const float*)d_in[1];
  const void* valid = d_in[2];
  const float* state = (const float*)d_in[3];
  const int* mask_id = (const int*)d_in[4];
  const float* extra = (const float*)d_in[5];
  const float* glob = (const float*)d_in[6];
  float* out = (float*)d_out;
  int* modep = (int*)d_ws;

  sample_kernel<<<BF, NTHR1, 0, stream>>>(xyz, valid, state, mask_id, extra, glob,
                                          in_sizes[2] / 4, modep, out);
  knn_kernel<<<BF * 128, NTHR2, 0, stream>>>(x, xyz, valid, modep, out);
}